// Round 5
// baseline (521.098 us; speedup 1.0000x reference)
//
#include <hip/hip_runtime.h>
#include <hip/hip_bf16.h>

#define H 128
#define LN_EPS 1e-5f

typedef __attribute__((ext_vector_type(8))) short bf16x8;
typedef __attribute__((ext_vector_type(4))) float f32x4;

static __device__ __forceinline__ unsigned short f2bf(float f) {
  unsigned u = __float_as_uint(f);
  unsigned r = (u + 0x7fff + ((u >> 16) & 1)) >> 16;
  return (unsigned short)r;
}
static __device__ __forceinline__ float bf2f(unsigned short s) {
  return __uint_as_float(((unsigned)s) << 16);
}

// ---------------- utility kernels ----------------

__global__ void zero_int_kernel(int* __restrict__ p, int n) {
  int i = blockIdx.x * blockDim.x + threadIdx.x;
  if (i < n) p[i] = 0;
}

// cvec[j] = bf[j] + sum_{r<128} Wf[r][j]   (the ones @ Wf[:128] term)
__global__ void prep_cvec_kernel(const float* __restrict__ Wf, const float* __restrict__ bf,
                                 float* __restrict__ cvec) {
  int j = threadIdx.x;
  float s = bf[j];
  for (int r = 0; r < H; ++r) s += Wf[r * H + j];
  cvec[j] = s;
}

__global__ void count_kernel(const int* __restrict__ ei, int E, int* __restrict__ cnt) {
  int e = blockIdx.x * blockDim.x + threadIdx.x;
  if (e < E) atomicAdd(&cnt[ei[E + e]], 1);  // dst = ei[1][e]
}

__global__ __launch_bounds__(1024) void scan_kernel(const int* __restrict__ cnt,
                                                    int* __restrict__ off,
                                                    int* __restrict__ pos, int N) {
  __shared__ int wtot[16];
  __shared__ int wbase[16];
  __shared__ int s_btot;
  __shared__ int s_carry;
  int tid = threadIdx.x, lane = tid & 63, wid = tid >> 6;
  if (tid == 0) s_carry = 0;
  __syncthreads();
  for (int base = 0; base < N; base += 4096) {
    int i0 = base + tid * 4;
    int v[4];
#pragma unroll
    for (int j = 0; j < 4; ++j) v[j] = (i0 + j < N) ? cnt[i0 + j] : 0;
    int s = v[0] + v[1] + v[2] + v[3];
    int incl = s;
#pragma unroll
    for (int o = 1; o < 64; o <<= 1) {
      int t = __shfl_up(incl, o, 64);
      if (lane >= o) incl += t;
    }
    if (lane == 63) wtot[wid] = incl;
    __syncthreads();
    if (tid == 0) {
      int run = 0;
      for (int w = 0; w < 16; ++w) { wbase[w] = run; run += wtot[w]; }
      s_btot = run;
    }
    __syncthreads();
    int e0 = s_carry + wbase[wid] + (incl - s);
#pragma unroll
    for (int j = 0; j < 4; ++j) {
      if (i0 + j < N) { off[i0 + j] = e0; pos[i0 + j] = e0; }
      e0 += v[j];
    }
    __syncthreads();
    if (tid == 0) s_carry += s_btot;
    __syncthreads();
  }
  if (tid == 0) off[N] = s_carry;
}

__global__ void fill_kernel(const int* __restrict__ ei, const float* __restrict__ ew, int E,
                            int* __restrict__ pos, int* __restrict__ csr_src,
                            float* __restrict__ csr_w) {
  int e = blockIdx.x * blockDim.x + threadIdx.x;
  if (e < E) {
    int d = ei[E + e];
    int p = atomicAdd(&pos[d], 1);
    csr_src[p] = ei[e];
    csr_w[p] = ew[e];
  }
}

// f32 -> bf16 bulk convert (n multiple of 8)
__global__ __launch_bounds__(256) void cvt_bf16_kernel(const float* __restrict__ in,
                                                       unsigned short* __restrict__ out,
                                                       long n) {
  long i = ((long)blockIdx.x * blockDim.x + threadIdx.x) * 8;
  if (i >= n) return;
  float4 v0 = *(const float4*)&in[i];
  float4 v1 = *(const float4*)&in[i + 4];
  unsigned short t[8];
  t[0] = f2bf(v0.x); t[1] = f2bf(v0.y); t[2] = f2bf(v0.z); t[3] = f2bf(v0.w);
  t[4] = f2bf(v1.x); t[5] = f2bf(v1.y); t[6] = f2bf(v1.z); t[7] = f2bf(v1.w);
  *(uint4*)&out[i] = *(uint4*)t;
}

// pack 9 [128x128] weight matrices into MFMA B-fragment layout:
// wpk[m*16384 + ((kk*8+nf)*64 + l)*8 + j] = bf16(W[kk*32 + (l>>4)*8 + j][nf*16 + (l&15)])
__global__ __launch_bounds__(256) void pack_w_kernel(const float* __restrict__ Wf,
                                                     const float* __restrict__ Wrel,
                                                     const float* __restrict__ Wroot,
                                                     const float* __restrict__ Wd1,
                                                     unsigned short* __restrict__ wpk) {
  int id = blockIdx.x * blockDim.x + threadIdx.x;  // 0 .. 9*2048-1
  if (id >= 9 * 2048) return;
  int l = id & 63, nf = (id >> 6) & 7, kk = (id >> 9) & 3, m = id >> 11;
  const float* src;
  if (m == 0) src = Wf + H * H;                       // Wf2 (h_old part)
  else if (m <= 3) src = Wrel + (size_t)(m - 1) * H * H;
  else if (m <= 6) src = Wroot + (size_t)(m - 4) * H * H;
  else src = Wd1 + (size_t)(m - 7) * H * H;           // Wd1a, Wd1b
  int col = nf * 16 + (l & 15);
  int kbase = kk * 32 + (l >> 4) * 8;
  unsigned short t[8];
#pragma unroll
  for (int j = 0; j < 8; ++j) t[j] = f2bf(src[(size_t)(kbase + j) * H + col]);
  *(uint4*)&wpk[(size_t)id * 8] = *(uint4*)t;
}

// ---------------- edge weight MLP v3: 16 lanes/edge, weights in registers ----------------
// ew[e] = sigmoid(relu(af@We1+be1)@We2+be2)
__global__ __launch_bounds__(256) void edge_weight_v3_kernel(
    const float* __restrict__ af, const float* __restrict__ We1, const float* __restrict__ be1,
    const float* __restrict__ We2, const float* __restrict__ be2, float* __restrict__ ew, int E) {
  int lane = threadIdx.x & 63;
  int sub = lane & 15;  // col group: cols sub*8 .. sub*8+7
  int grp = lane >> 4;  // which of 4 edges in this wave
  float w1[8][8], b1[8], w2[8];
#pragma unroll
  for (int i = 0; i < 8; ++i)
#pragma unroll
    for (int c = 0; c < 8; ++c) w1[i][c] = We1[i * H + sub * 8 + c];
#pragma unroll
  for (int c = 0; c < 8; ++c) { b1[c] = be1[sub * 8 + c]; w2[c] = We2[sub * 8 + c]; }
  float b2 = be2[0];
  int gw = (blockIdx.x * blockDim.x + threadIdx.x) >> 6;
  int nw = (gridDim.x * blockDim.x) >> 6;
  int n4 = (E + 3) >> 2;
  for (int e4 = gw; e4 < n4; e4 += nw) {
    int e = e4 * 4 + grp;
    bool valid = e < E;
    int ee = valid ? e : E - 1;
    float4 a0 = *(const float4*)&af[(size_t)ee * 8];
    float4 a1 = *(const float4*)&af[(size_t)ee * 8 + 4];
    float afv[8] = {a0.x, a0.y, a0.z, a0.w, a1.x, a1.y, a1.z, a1.w};
    float t[8];
#pragma unroll
    for (int c = 0; c < 8; ++c) t[c] = b1[c];
#pragma unroll
    for (int i = 0; i < 8; ++i)
#pragma unroll
      for (int c = 0; c < 8; ++c) t[c] += afv[i] * w1[i][c];
    float p = 0.f;
#pragma unroll
    for (int c = 0; c < 8; ++c) p += fmaxf(t[c], 0.f) * w2[c];
    p += __shfl_xor(p, 1, 64);
    p += __shfl_xor(p, 2, 64);
    p += __shfl_xor(p, 4, 64);
    p += __shfl_xor(p, 8, 64);
    if (valid && sub == 0) {
      float s = p + b2;
      ew[e] = 1.f / (1.f + expf(-s));
    }
  }
}

// ---------------- MFMA GEMM: Y = act(X1@W1 [+ X2@W2] + bias) ----------------
// X row-major bf16 [M,128]; W pre-packed fragment layout; OUT_MODE 0: f32, 1: bf16+relu, 2: bf16
template <bool DUAL, int OUT_MODE>
__global__ __launch_bounds__(256) void mfma_gemm_kernel(
    const unsigned short* __restrict__ X1, const unsigned short* __restrict__ Wp1,
    const unsigned short* __restrict__ X2, const unsigned short* __restrict__ Wp2,
    const float* __restrict__ bias, void* __restrict__ Yv, int M) {
  int l = threadIdx.x & 63, w = threadIdx.x >> 6;
  int lr = l & 15, lg = l >> 4;
  int m0 = blockIdx.x * 256 + w * 64;
  f32x4 acc[4][8] = {};
  const int nkk = DUAL ? 8 : 4;
  for (int kk = 0; kk < nkk; ++kk) {
    const unsigned short* X = (DUAL && kk >= 4) ? X2 : X1;
    const unsigned short* Wp = (DUAL && kk >= 4) ? Wp2 : Wp1;
    int k4 = kk & 3;
    bf16x8 a[4];
#pragma unroll
    for (int mi = 0; mi < 4; ++mi) {
      int row = m0 + mi * 16 + lr;
      if (row >= M) row = M - 1;
      a[mi] = *(const bf16x8*)&X[(size_t)row * H + k4 * 32 + lg * 8];
    }
#pragma unroll
    for (int nf = 0; nf < 8; ++nf) {
      bf16x8 b = *(const bf16x8*)&Wp[(size_t)(k4 * 8 + nf) * 512 + l * 8];
#pragma unroll
      for (int mi = 0; mi < 4; ++mi)
        acc[mi][nf] = __builtin_amdgcn_mfma_f32_16x16x32_bf16(a[mi], b, acc[mi][nf], 0, 0, 0);
    }
  }
  float bv[8];
#pragma unroll
  for (int nf = 0; nf < 8; ++nf) bv[nf] = bias ? bias[nf * 16 + lr] : 0.f;
#pragma unroll
  for (int mi = 0; mi < 4; ++mi) {
#pragma unroll
    for (int r = 0; r < 4; ++r) {
      int row = m0 + mi * 16 + lg * 4 + r;
      if (row < M) {
#pragma unroll
        for (int nf = 0; nf < 8; ++nf) {
          float v = acc[mi][nf][r] + bv[nf];
          if (OUT_MODE == 1) v = fmaxf(v, 0.f);
          int col = nf * 16 + lr;
          if (OUT_MODE == 0) ((float*)Yv)[(size_t)row * H + col] = v;
          else ((unsigned short*)Yv)[(size_t)row * H + col] = f2bf(v);
        }
      }
    }
  }
}

// ---------------- gather: agg[n] = sum_in-edges w * x[src]  (wave/node, 4-deep unroll) ----------------
__global__ __launch_bounds__(256) void gather_agg_bf_kernel(
    const unsigned short* __restrict__ xbf, const int* __restrict__ off,
    const int* __restrict__ csr_src, const float* __restrict__ csr_w,
    unsigned short* __restrict__ aggbf, int N) {
  int gw = (blockIdx.x * blockDim.x + threadIdx.x) >> 6;
  int lane = threadIdx.x & 63;
  int nw = (gridDim.x * blockDim.x) >> 6;
  for (int n = gw; n < N; n += nw) {
    int s0 = off[n], s1 = off[n + 1];
    float ax = 0.f, ay = 0.f;
    int idx = s0;
    for (; idx + 4 <= s1; idx += 4) {
      int src0 = csr_src[idx + 0], src1 = csr_src[idx + 1];
      int src2 = csr_src[idx + 2], src3 = csr_src[idx + 3];
      float w0 = csr_w[idx + 0], w1 = csr_w[idx + 1];
      float w2 = csr_w[idx + 2], w3 = csr_w[idx + 3];
      unsigned v0 = *(const unsigned*)&xbf[(size_t)src0 * H + lane * 2];
      unsigned v1 = *(const unsigned*)&xbf[(size_t)src1 * H + lane * 2];
      unsigned v2 = *(const unsigned*)&xbf[(size_t)src2 * H + lane * 2];
      unsigned v3 = *(const unsigned*)&xbf[(size_t)src3 * H + lane * 2];
      ax += w0 * bf2f((unsigned short)(v0 & 0xffffu));
      ay += w0 * bf2f((unsigned short)(v0 >> 16));
      ax += w1 * bf2f((unsigned short)(v1 & 0xffffu));
      ay += w1 * bf2f((unsigned short)(v1 >> 16));
      ax += w2 * bf2f((unsigned short)(v2 & 0xffffu));
      ay += w2 * bf2f((unsigned short)(v2 >> 16));
      ax += w3 * bf2f((unsigned short)(v3 & 0xffffu));
      ay += w3 * bf2f((unsigned short)(v3 >> 16));
    }
    for (; idx < s1; ++idx) {
      int src = csr_src[idx];
      float w = csr_w[idx];
      unsigned v = *(const unsigned*)&xbf[(size_t)src * H + lane * 2];
      ax += w * bf2f((unsigned short)(v & 0xffffu));
      ay += w * bf2f((unsigned short)(v >> 16));
    }
    unsigned o = (unsigned)f2bf(ax) | ((unsigned)f2bf(ay) << 16);
    *(unsigned*)&aggbf[(size_t)n * H + lane * 2] = o;
  }
}

// ---------------- LayerNorm+relu+residual: x = bf16(relu(LN(h)*g+b) + x) ----------------
__global__ __launch_bounds__(256) void ln_relu_res_bf_kernel(
    const float* __restrict__ h, unsigned short* __restrict__ xbf,
    const float* __restrict__ gamma, const float* __restrict__ beta, int N) {
  int gw = (blockIdx.x * blockDim.x + threadIdx.x) >> 6;
  int lane = threadIdx.x & 63;
  int nw = (gridDim.x * blockDim.x) >> 6;
  for (int n = gw; n < N; n += nw) {
    float2 v = *(const float2*)&h[(size_t)n * H + lane * 2];
    float tot = v.x + v.y;
#pragma unroll
    for (int o = 32; o > 0; o >>= 1) tot += __shfl_xor(tot, o, 64);
    float mu = tot * (1.0f / H);
    float d0 = v.x - mu, d1 = v.y - mu;
    float s2 = d0 * d0 + d1 * d1;
#pragma unroll
    for (int o = 32; o > 0; o >>= 1) s2 += __shfl_xor(s2, o, 64);
    float r = rsqrtf(s2 * (1.0f / H) + LN_EPS);
    float2 g = *(const float2*)&gamma[lane * 2];
    float2 b = *(const float2*)&beta[lane * 2];
    unsigned xo = *(const unsigned*)&xbf[(size_t)n * H + lane * 2];
    float o0 = fmaxf(d0 * r * g.x + b.x, 0.f) + bf2f((unsigned short)(xo & 0xffffu));
    float o1 = fmaxf(d1 * r * g.y + b.y, 0.f) + bf2f((unsigned short)(xo >> 16));
    unsigned res = (unsigned)f2bf(o0) | ((unsigned)f2bf(o1) << 16);
    *(unsigned*)&xbf[(size_t)n * H + lane * 2] = res;
  }
}

// ---------------- edge decoder v3: 16 lanes/edge, weights in registers ----------------
// out[e] = relu(A[src]+B[dst]+af@Wd1c)·Wd2 + bd2
__global__ __launch_bounds__(256) void edge_out_v3_kernel(
    const int* __restrict__ ei, const float* __restrict__ af,
    const unsigned short* __restrict__ A, const unsigned short* __restrict__ B,
    const float* __restrict__ Wd1c, const float* __restrict__ Wd2,
    const float* __restrict__ bd2, float* __restrict__ out, int E) {
  int lane = threadIdx.x & 63;
  int sub = lane & 15;
  int grp = lane >> 4;
  float wc[8][8], w2[8];
#pragma unroll
  for (int i = 0; i < 8; ++i)
#pragma unroll
    for (int c = 0; c < 8; ++c) wc[i][c] = Wd1c[i * H + sub * 8 + c];
#pragma unroll
  for (int c = 0; c < 8; ++c) w2[c] = Wd2[sub * 8 + c];
  float b2 = bd2[0];
  int gw = (blockIdx.x * blockDim.x + threadIdx.x) >> 6;
  int nw = (gridDim.x * blockDim.x) >> 6;
  int n4 = (E + 3) >> 2;
  for (int e4 = gw; e4 < n4; e4 += nw) {
    int e = e4 * 4 + grp;
    bool valid = e < E;
    int ee = valid ? e : E - 1;
    int s = ei[ee], d = ei[E + ee];
    uint4 va = *(const uint4*)&A[(size_t)s * H + sub * 8];
    uint4 vb = *(const uint4*)&B[(size_t)d * H + sub * 8];
    float4 a0 = *(const float4*)&af[(size_t)ee * 8];
    float4 a1 = *(const float4*)&af[(size_t)ee * 8 + 4];
    float afv[8] = {a0.x, a0.y, a0.z, a0.w, a1.x, a1.y, a1.z, a1.w};
    const unsigned* pa = (const unsigned*)&va;
    const unsigned* pb = (const unsigned*)&vb;
    float t[8];
#pragma unroll
    for (int q = 0; q < 4; ++q) {
      unsigned av = pa[q], bv = pb[q];
      t[q * 2 + 0] = bf2f((unsigned short)(av & 0xffffu)) + bf2f((unsigned short)(bv & 0xffffu));
      t[q * 2 + 1] = bf2f((unsigned short)(av >> 16)) + bf2f((unsigned short)(bv >> 16));
    }
#pragma unroll
    for (int i = 0; i < 8; ++i)
#pragma unroll
      for (int c = 0; c < 8; ++c) t[c] += afv[i] * wc[i][c];
    float p = 0.f;
#pragma unroll
    for (int c = 0; c < 8; ++c) p += fmaxf(t[c], 0.f) * w2[c];
    p += __shfl_xor(p, 1, 64);
    p += __shfl_xor(p, 2, 64);
    p += __shfl_xor(p, 4, 64);
    p += __shfl_xor(p, 8, 64);
    if (valid && sub == 0) out[e] = p + b2;
  }
}

// ---------------- launch ----------------
extern "C" void kernel_launch(void* const* d_in, const int* in_sizes, int n_in, void* d_out,
                              int out_size, void* d_ws, size_t ws_size, hipStream_t stream) {
  const int* ei = (const int*)d_in[0];
  const float* af = (const float*)d_in[1];
  const float* h_old = (const float*)d_in[2];
  const float* Wf = (const float*)d_in[4];
  const float* bf = (const float*)d_in[5];
  const float* We1 = (const float*)d_in[6];
  const float* be1 = (const float*)d_in[7];
  const float* We2 = (const float*)d_in[8];
  const float* be2 = (const float*)d_in[9];
  const float* Wrel = (const float*)d_in[10];
  const float* brel = (const float*)d_in[11];
  const float* Wroot = (const float*)d_in[12];
  const float* gamma = (const float*)d_in[13];
  const float* beta = (const float*)d_in[14];
  const float* Wd1 = (const float*)d_in[15];
  const float* bd1 = (const float*)d_in[16];
  const float* Wd2 = (const float*)d_in[17];
  const float* bd2 = (const float*)d_in[18];
  const int N = in_sizes[2] / H;
  const int E = in_sizes[1] / 8;
  float* out = (float*)d_out;

  char* p = (char*)d_ws;
  auto alloc = [&](size_t b) { char* r = p; p += (b + 255) & ~(size_t)255; return r; };
  int* cnt = (int*)alloc((size_t)N * 4);
  int* pos = (int*)alloc((size_t)N * 4);
  int* off = (int*)alloc((size_t)(N + 1) * 4);
  int* csr_src = (int*)alloc((size_t)E * 4);
  float* csr_w = (float*)alloc((size_t)E * 4);
  float* ew = (float*)alloc((size_t)E * 4);
  float* cvec = (float*)alloc(H * 4);
  unsigned short* wpk = (unsigned short*)alloc((size_t)9 * 16384 * 2);
  unsigned short* xbf = (unsigned short*)alloc((size_t)N * H * 2);
  unsigned short* buf1 = (unsigned short*)alloc((size_t)N * H * 2);  // hbf / aggbf
  float* hbuf = (float*)alloc((size_t)N * H * 4);                    // h f32 / Abf+Bbf

  unsigned short* hbf = buf1;
  unsigned short* aggbf = buf1;
  unsigned short* Abf = (unsigned short*)hbuf;
  unsigned short* Bbf = (unsigned short*)hbuf + (size_t)N * H;

  hipLaunchKernelGGL(zero_int_kernel, dim3((N + 255) / 256), dim3(256), 0, stream, cnt, N);
  hipLaunchKernelGGL(prep_cvec_kernel, dim3(1), dim3(H), 0, stream, Wf, bf, cvec);
  hipLaunchKernelGGL(count_kernel, dim3((E + 255) / 256), dim3(256), 0, stream, ei, E, cnt);
  hipLaunchKernelGGL(scan_kernel, dim3(1), dim3(1024), 0, stream, cnt, off, pos, N);
  hipLaunchKernelGGL(edge_weight_v3_kernel, dim3(4096), dim3(256), 0, stream, af, We1, be1,
                     We2, be2, ew, E);
  hipLaunchKernelGGL(fill_kernel, dim3((E + 255) / 256), dim3(256), 0, stream, ei, ew, E, pos,
                     csr_src, csr_w);
  hipLaunchKernelGGL(cvt_bf16_kernel, dim3(((long)N * H / 8 + 255) / 256), dim3(256), 0, stream,
                     h_old, hbf, (long)N * H);
  hipLaunchKernelGGL(pack_w_kernel, dim3(72), dim3(256), 0, stream, Wf, Wrel, Wroot, Wd1, wpk);

  int gblocks = (N + 255) / 256;
  // x = relu(h_old @ Wf2 + cvec) -> bf16
  hipLaunchKernelGGL((mfma_gemm_kernel<false, 1>), dim3(gblocks), dim3(256), 0, stream, hbf,
                     wpk, (const unsigned short*)nullptr, (const unsigned short*)nullptr, cvec,
                     xbf, N);

  for (int l = 0; l < 3; ++l) {
    hipLaunchKernelGGL(gather_agg_bf_kernel, dim3((N + 3) / 4), dim3(256), 0, stream, xbf, off,
                       csr_src, csr_w, aggbf, N);
    hipLaunchKernelGGL((mfma_gemm_kernel<true, 0>), dim3(gblocks), dim3(256), 0, stream, aggbf,
                       wpk + (size_t)(1 + l) * 16384, xbf, wpk + (size_t)(4 + l) * 16384,
                       brel + l * H, hbuf, N);
    hipLaunchKernelGGL(ln_relu_res_bf_kernel, dim3((N + 3) / 4), dim3(256), 0, stream, hbuf,
                       xbf, gamma + l * H, beta + l * H, N);
  }

  // decoder per-node projections: A = x@Wd1a + bd1 ; B = x@Wd1b  (bf16 outputs)
  hipLaunchKernelGGL((mfma_gemm_kernel<false, 2>), dim3(gblocks), dim3(256), 0, stream, xbf,
                     wpk + (size_t)7 * 16384, (const unsigned short*)nullptr,
                     (const unsigned short*)nullptr, bd1, Abf, N);
  hipLaunchKernelGGL((mfma_gemm_kernel<false, 2>), dim3(gblocks), dim3(256), 0, stream, xbf,
                     wpk + (size_t)8 * 16384, (const unsigned short*)nullptr,
                     (const unsigned short*)nullptr, (const float*)nullptr, Bbf, N);
  hipLaunchKernelGGL(edge_out_v3_kernel, dim3(4096), dim3(256), 0, stream, ei, af, Abf, Bbf,
                     Wd1 + 2 * H * H, Wd2, bd2, out, E);
}

// Round 6
// 512.696 us; speedup vs baseline: 1.0164x; 1.0164x over previous
//
#include <hip/hip_runtime.h>
#include <hip/hip_bf16.h>

#define H 128
#define LN_EPS 1e-5f

typedef __attribute__((ext_vector_type(8))) short bf16x8;
typedef __attribute__((ext_vector_type(4))) float f32x4;

static __device__ __forceinline__ unsigned short f2bf(float f) {
  unsigned u = __float_as_uint(f);
  unsigned r = (u + 0x7fff + ((u >> 16) & 1)) >> 16;
  return (unsigned short)r;
}
static __device__ __forceinline__ float bf2f(unsigned short s) {
  return __uint_as_float(((unsigned)s) << 16);
}

// ---------------- utility kernels ----------------

__global__ void zero_int_kernel(int* __restrict__ p, int n) {
  int i = blockIdx.x * blockDim.x + threadIdx.x;
  if (i < n) p[i] = 0;
}

// cvec[j] = bf[j] + sum_{r<128} Wf[r][j]   (the ones @ Wf[:128] term)
__global__ void prep_cvec_kernel(const float* __restrict__ Wf, const float* __restrict__ bf,
                                 float* __restrict__ cvec) {
  int j = threadIdx.x;
  float s = bf[j];
  for (int r = 0; r < H; ++r) s += Wf[r * H + j];
  cvec[j] = s;
}

__global__ void count_kernel(const int* __restrict__ ei, int E, int* __restrict__ cnt) {
  int e = blockIdx.x * blockDim.x + threadIdx.x;
  if (e < E) atomicAdd(&cnt[ei[E + e]], 1);  // dst = ei[1][e]
}

__global__ __launch_bounds__(1024) void scan_kernel(const int* __restrict__ cnt,
                                                    int* __restrict__ off,
                                                    int* __restrict__ pos, int N) {
  __shared__ int wtot[16];
  __shared__ int wbase[16];
  __shared__ int s_btot;
  __shared__ int s_carry;
  int tid = threadIdx.x, lane = tid & 63, wid = tid >> 6;
  if (tid == 0) s_carry = 0;
  __syncthreads();
  for (int base = 0; base < N; base += 4096) {
    int i0 = base + tid * 4;
    int v[4];
#pragma unroll
    for (int j = 0; j < 4; ++j) v[j] = (i0 + j < N) ? cnt[i0 + j] : 0;
    int s = v[0] + v[1] + v[2] + v[3];
    int incl = s;
#pragma unroll
    for (int o = 1; o < 64; o <<= 1) {
      int t = __shfl_up(incl, o, 64);
      if (lane >= o) incl += t;
    }
    if (lane == 63) wtot[wid] = incl;
    __syncthreads();
    if (tid == 0) {
      int run = 0;
      for (int w = 0; w < 16; ++w) { wbase[w] = run; run += wtot[w]; }
      s_btot = run;
    }
    __syncthreads();
    int e0 = s_carry + wbase[wid] + (incl - s);
#pragma unroll
    for (int j = 0; j < 4; ++j) {
      if (i0 + j < N) { off[i0 + j] = e0; pos[i0 + j] = e0; }
      e0 += v[j];
    }
    __syncthreads();
    if (tid == 0) s_carry += s_btot;
    __syncthreads();
  }
  if (tid == 0) off[N] = s_carry;
}

__global__ void fill_kernel(const int* __restrict__ ei, const float* __restrict__ ew, int E,
                            int* __restrict__ pos, int* __restrict__ csr_src,
                            float* __restrict__ csr_w) {
  int e = blockIdx.x * blockDim.x + threadIdx.x;
  if (e < E) {
    int d = ei[E + e];
    int p = atomicAdd(&pos[d], 1);
    csr_src[p] = ei[e];
    csr_w[p] = ew[e];
  }
}

// f32 -> bf16 bulk convert (n multiple of 8)
__global__ __launch_bounds__(256) void cvt_bf16_kernel(const float* __restrict__ in,
                                                       unsigned short* __restrict__ out,
                                                       long n) {
  long i = ((long)blockIdx.x * blockDim.x + threadIdx.x) * 8;
  if (i >= n) return;
  float4 v0 = *(const float4*)&in[i];
  float4 v1 = *(const float4*)&in[i + 4];
  unsigned short t[8];
  t[0] = f2bf(v0.x); t[1] = f2bf(v0.y); t[2] = f2bf(v0.z); t[3] = f2bf(v0.w);
  t[4] = f2bf(v1.x); t[5] = f2bf(v1.y); t[6] = f2bf(v1.z); t[7] = f2bf(v1.w);
  *(uint4*)&out[i] = *(uint4*)t;
}

// pack 9 [128x128] weight matrices into MFMA B-fragment layout:
// wpk[m*16384 + ((kk*8+nf)*64 + l)*8 + j] = bf16(W[kk*32 + (l>>4)*8 + j][nf*16 + (l&15)])
__global__ __launch_bounds__(256) void pack_w_kernel(const float* __restrict__ Wf,
                                                     const float* __restrict__ Wrel,
                                                     const float* __restrict__ Wroot,
                                                     const float* __restrict__ Wd1,
                                                     unsigned short* __restrict__ wpk) {
  int id = blockIdx.x * blockDim.x + threadIdx.x;  // 0 .. 9*2048-1
  if (id >= 9 * 2048) return;
  int l = id & 63, nf = (id >> 6) & 7, kk = (id >> 9) & 3, m = id >> 11;
  const float* src;
  if (m == 0) src = Wf + H * H;                       // Wf2 (h_old part)
  else if (m <= 3) src = Wrel + (size_t)(m - 1) * H * H;
  else if (m <= 6) src = Wroot + (size_t)(m - 4) * H * H;
  else src = Wd1 + (size_t)(m - 7) * H * H;           // Wd1a, Wd1b
  int col = nf * 16 + (l & 15);
  int kbase = kk * 32 + (l >> 4) * 8;
  unsigned short t[8];
#pragma unroll
  for (int j = 0; j < 8; ++j) t[j] = f2bf(src[(size_t)(kbase + j) * H + col]);
  *(uint4*)&wpk[(size_t)id * 8] = *(uint4*)t;
}

// ---------------- edge weight MLP v3: 16 lanes/edge, weights in registers ----------------
// ew[e] = sigmoid(relu(af@We1+be1)@We2+be2)
__global__ __launch_bounds__(256) void edge_weight_v3_kernel(
    const float* __restrict__ af, const float* __restrict__ We1, const float* __restrict__ be1,
    const float* __restrict__ We2, const float* __restrict__ be2, float* __restrict__ ew, int E) {
  int lane = threadIdx.x & 63;
  int sub = lane & 15;  // col group: cols sub*8 .. sub*8+7
  int grp = lane >> 4;  // which of 4 edges in this wave
  float w1[8][8], b1[8], w2[8];
#pragma unroll
  for (int i = 0; i < 8; ++i)
#pragma unroll
    for (int c = 0; c < 8; ++c) w1[i][c] = We1[i * H + sub * 8 + c];
#pragma unroll
  for (int c = 0; c < 8; ++c) { b1[c] = be1[sub * 8 + c]; w2[c] = We2[sub * 8 + c]; }
  float b2 = be2[0];
  int gw = (blockIdx.x * blockDim.x + threadIdx.x) >> 6;
  int nw = (gridDim.x * blockDim.x) >> 6;
  int n4 = (E + 3) >> 2;
  for (int e4 = gw; e4 < n4; e4 += nw) {
    int e = e4 * 4 + grp;
    bool valid = e < E;
    int ee = valid ? e : E - 1;
    float4 a0 = *(const float4*)&af[(size_t)ee * 8];
    float4 a1 = *(const float4*)&af[(size_t)ee * 8 + 4];
    float afv[8] = {a0.x, a0.y, a0.z, a0.w, a1.x, a1.y, a1.z, a1.w};
    float t[8];
#pragma unroll
    for (int c = 0; c < 8; ++c) t[c] = b1[c];
#pragma unroll
    for (int i = 0; i < 8; ++i)
#pragma unroll
      for (int c = 0; c < 8; ++c) t[c] += afv[i] * w1[i][c];
    float p = 0.f;
#pragma unroll
    for (int c = 0; c < 8; ++c) p += fmaxf(t[c], 0.f) * w2[c];
    p += __shfl_xor(p, 1, 64);
    p += __shfl_xor(p, 2, 64);
    p += __shfl_xor(p, 4, 64);
    p += __shfl_xor(p, 8, 64);
    if (valid && sub == 0) {
      float s = p + b2;
      ew[e] = 1.f / (1.f + expf(-s));
    }
  }
}

// ---------------- MFMA GEMM: Y = act(X1@W1 [+ X2@W2] + bias) ----------------
// X row-major bf16 [M,128]; W pre-packed fragment layout; OUT_MODE 0: f32, 1: bf16+relu, 2: bf16
template <bool DUAL, int OUT_MODE>
__global__ __launch_bounds__(256) void mfma_gemm_kernel(
    const unsigned short* __restrict__ X1, const unsigned short* __restrict__ Wp1,
    const unsigned short* __restrict__ X2, const unsigned short* __restrict__ Wp2,
    const float* __restrict__ bias, void* __restrict__ Yv, int M) {
  int l = threadIdx.x & 63, w = threadIdx.x >> 6;
  int lr = l & 15, lg = l >> 4;
  int m0 = blockIdx.x * 256 + w * 64;
  f32x4 acc[4][8] = {};
  const int nkk = DUAL ? 8 : 4;
  for (int kk = 0; kk < nkk; ++kk) {
    const unsigned short* X = (DUAL && kk >= 4) ? X2 : X1;
    const unsigned short* Wp = (DUAL && kk >= 4) ? Wp2 : Wp1;
    int k4 = kk & 3;
    bf16x8 a[4];
#pragma unroll
    for (int mi = 0; mi < 4; ++mi) {
      int row = m0 + mi * 16 + lr;
      if (row >= M) row = M - 1;
      a[mi] = *(const bf16x8*)&X[(size_t)row * H + k4 * 32 + lg * 8];
    }
#pragma unroll
    for (int nf = 0; nf < 8; ++nf) {
      bf16x8 b = *(const bf16x8*)&Wp[(size_t)(k4 * 8 + nf) * 512 + l * 8];
#pragma unroll
      for (int mi = 0; mi < 4; ++mi)
        acc[mi][nf] = __builtin_amdgcn_mfma_f32_16x16x32_bf16(a[mi], b, acc[mi][nf], 0, 0, 0);
    }
  }
  float bv[8];
#pragma unroll
  for (int nf = 0; nf < 8; ++nf) bv[nf] = bias ? bias[nf * 16 + lr] : 0.f;
#pragma unroll
  for (int mi = 0; mi < 4; ++mi) {
#pragma unroll
    for (int r = 0; r < 4; ++r) {
      int row = m0 + mi * 16 + lg * 4 + r;
      if (row < M) {
#pragma unroll
        for (int nf = 0; nf < 8; ++nf) {
          float v = acc[mi][nf][r] + bv[nf];
          if (OUT_MODE == 1) v = fmaxf(v, 0.f);
          int col = nf * 16 + lr;
          if (OUT_MODE == 0) ((float*)Yv)[(size_t)row * H + col] = v;
          else ((unsigned short*)Yv)[(size_t)row * H + col] = f2bf(v);
        }
      }
    }
  }
}

// ---------------- gather: agg[n] = sum_in-edges w * x[src]  (wave/node, 4-deep unroll) ----------------
__global__ __launch_bounds__(256) void gather_agg_bf_kernel(
    const unsigned short* __restrict__ xbf, const int* __restrict__ off,
    const int* __restrict__ csr_src, const float* __restrict__ csr_w,
    unsigned short* __restrict__ aggbf, int N) {
  int gw = (blockIdx.x * blockDim.x + threadIdx.x) >> 6;
  int lane = threadIdx.x & 63;
  int nw = (gridDim.x * blockDim.x) >> 6;
  for (int n = gw; n < N; n += nw) {
    int s0 = off[n], s1 = off[n + 1];
    float ax = 0.f, ay = 0.f;
    int idx = s0;
    for (; idx + 4 <= s1; idx += 4) {
      int src0 = csr_src[idx + 0], src1 = csr_src[idx + 1];
      int src2 = csr_src[idx + 2], src3 = csr_src[idx + 3];
      float w0 = csr_w[idx + 0], w1 = csr_w[idx + 1];
      float w2 = csr_w[idx + 2], w3 = csr_w[idx + 3];
      unsigned v0 = *(const unsigned*)&xbf[(size_t)src0 * H + lane * 2];
      unsigned v1 = *(const unsigned*)&xbf[(size_t)src1 * H + lane * 2];
      unsigned v2 = *(const unsigned*)&xbf[(size_t)src2 * H + lane * 2];
      unsigned v3 = *(const unsigned*)&xbf[(size_t)src3 * H + lane * 2];
      ax += w0 * bf2f((unsigned short)(v0 & 0xffffu));
      ay += w0 * bf2f((unsigned short)(v0 >> 16));
      ax += w1 * bf2f((unsigned short)(v1 & 0xffffu));
      ay += w1 * bf2f((unsigned short)(v1 >> 16));
      ax += w2 * bf2f((unsigned short)(v2 & 0xffffu));
      ay += w2 * bf2f((unsigned short)(v2 >> 16));
      ax += w3 * bf2f((unsigned short)(v3 & 0xffffu));
      ay += w3 * bf2f((unsigned short)(v3 >> 16));
    }
    for (; idx < s1; ++idx) {
      int src = csr_src[idx];
      float w = csr_w[idx];
      unsigned v = *(const unsigned*)&xbf[(size_t)src * H + lane * 2];
      ax += w * bf2f((unsigned short)(v & 0xffffu));
      ay += w * bf2f((unsigned short)(v >> 16));
    }
    unsigned o = (unsigned)f2bf(ax) | ((unsigned)f2bf(ay) << 16);
    *(unsigned*)&aggbf[(size_t)n * H + lane * 2] = o;
  }
}

// ---------------- LayerNorm+relu+residual: x = bf16(relu(LN(h)*g+b) + x) ----------------
__global__ __launch_bounds__(256) void ln_relu_res_bf_kernel(
    const float* __restrict__ h, unsigned short* __restrict__ xbf,
    const float* __restrict__ gamma, const float* __restrict__ beta, int N) {
  int gw = (blockIdx.x * blockDim.x + threadIdx.x) >> 6;
  int lane = threadIdx.x & 63;
  int nw = (gridDim.x * blockDim.x) >> 6;
  for (int n = gw; n < N; n += nw) {
    float2 v = *(const float2*)&h[(size_t)n * H + lane * 2];
    float tot = v.x + v.y;
#pragma unroll
    for (int o = 32; o > 0; o >>= 1) tot += __shfl_xor(tot, o, 64);
    float mu = tot * (1.0f / H);
    float d0 = v.x - mu, d1 = v.y - mu;
    float s2 = d0 * d0 + d1 * d1;
#pragma unroll
    for (int o = 32; o > 0; o >>= 1) s2 += __shfl_xor(s2, o, 64);
    float r = rsqrtf(s2 * (1.0f / H) + LN_EPS);
    float2 g = *(const float2*)&gamma[lane * 2];
    float2 b = *(const float2*)&beta[lane * 2];
    unsigned xo = *(const unsigned*)&xbf[(size_t)n * H + lane * 2];
    float o0 = fmaxf(d0 * r * g.x + b.x, 0.f) + bf2f((unsigned short)(xo & 0xffffu));
    float o1 = fmaxf(d1 * r * g.y + b.y, 0.f) + bf2f((unsigned short)(xo >> 16));
    unsigned res = (unsigned)f2bf(o0) | ((unsigned)f2bf(o1) << 16);
    *(unsigned*)&xbf[(size_t)n * H + lane * 2] = res;
  }
}

// ---------------- edge decoder v3: 16 lanes/edge, weights in registers ----------------
// out[e] = relu(A[src]+B[dst]+af@Wd1c)·Wd2 + bd2
__global__ __launch_bounds__(256) void edge_out_v3_kernel(
    const int* __restrict__ ei, const float* __restrict__ af,
    const unsigned short* __restrict__ A, const unsigned short* __restrict__ B,
    const float* __restrict__ Wd1c, const float* __restrict__ Wd2,
    const float* __restrict__ bd2, float* __restrict__ out, int E) {
  int lane = threadIdx.x & 63;
  int sub = lane & 15;
  int grp = lane >> 4;
  float wc[8][8], w2[8];
#pragma unroll
  for (int i = 0; i < 8; ++i)
#pragma unroll
    for (int c = 0; c < 8; ++c) wc[i][c] = Wd1c[i * H + sub * 8 + c];
#pragma unroll
  for (int c = 0; c < 8; ++c) w2[c] = Wd2[sub * 8 + c];
  float b2 = bd2[0];
  int gw = (blockIdx.x * blockDim.x + threadIdx.x) >> 6;
  int nw = (gridDim.x * blockDim.x) >> 6;
  int n4 = (E + 3) >> 2;
  for (int e4 = gw; e4 < n4; e4 += nw) {
    int e = e4 * 4 + grp;
    bool valid = e < E;
    int ee = valid ? e : E - 1;
    int s = ei[ee], d = ei[E + ee];
    uint4 va = *(const uint4*)&A[(size_t)s * H + sub * 8];
    uint4 vb = *(const uint4*)&B[(size_t)d * H + sub * 8];
    float4 a0 = *(const float4*)&af[(size_t)ee * 8];
    float4 a1 = *(const float4*)&af[(size_t)ee * 8 + 4];
    float afv[8] = {a0.x, a0.y, a0.z, a0.w, a1.x, a1.y, a1.z, a1.w};
    const unsigned* pa = (const unsigned*)&va;
    const unsigned* pb = (const unsigned*)&vb;
    float t[8];
#pragma unroll
    for (int q = 0; q < 4; ++q) {
      unsigned av = pa[q], bv = pb[q];
      t[q * 2 + 0] = bf2f((unsigned short)(av & 0xffffu)) + bf2f((unsigned short)(bv & 0xffffu));
      t[q * 2 + 1] = bf2f((unsigned short)(av >> 16)) + bf2f((unsigned short)(bv >> 16));
    }
#pragma unroll
    for (int i = 0; i < 8; ++i)
#pragma unroll
      for (int c = 0; c < 8; ++c) t[c] += afv[i] * wc[i][c];
    float p = 0.f;
#pragma unroll
    for (int c = 0; c < 8; ++c) p += fmaxf(t[c], 0.f) * w2[c];
    p += __shfl_xor(p, 1, 64);
    p += __shfl_xor(p, 2, 64);
    p += __shfl_xor(p, 4, 64);
    p += __shfl_xor(p, 8, 64);
    if (valid && sub == 0) out[e] = p + b2;
  }
}

// ---------------- launch ----------------
extern "C" void kernel_launch(void* const* d_in, const int* in_sizes, int n_in, void* d_out,
                              int out_size, void* d_ws, size_t ws_size, hipStream_t stream) {
  const int* ei = (const int*)d_in[0];
  const float* af = (const float*)d_in[1];
  const float* h_old = (const float*)d_in[2];
  const float* Wf = (const float*)d_in[4];
  const float* bf = (const float*)d_in[5];
  const float* We1 = (const float*)d_in[6];
  const float* be1 = (const float*)d_in[7];
  const float* We2 = (const float*)d_in[8];
  const float* be2 = (const float*)d_in[9];
  const float* Wrel = (const float*)d_in[10];
  const float* brel = (const float*)d_in[11];
  const float* Wroot = (const float*)d_in[12];
  const float* gamma = (const float*)d_in[13];
  const float* beta = (const float*)d_in[14];
  const float* Wd1 = (const float*)d_in[15];
  const float* bd1 = (const float*)d_in[16];
  const float* Wd2 = (const float*)d_in[17];
  const float* bd2 = (const float*)d_in[18];
  const int N = in_sizes[2] / H;
  const int E = in_sizes[1] / 8;
  float* out = (float*)d_out;

  char* p = (char*)d_ws;
  auto alloc = [&](size_t b) { char* r = p; p += (b + 255) & ~(size_t)255; return r; };
  int* cnt = (int*)alloc((size_t)N * 4);
  int* pos = (int*)alloc((size_t)N * 4);
  int* off = (int*)alloc((size_t)(N + 1) * 4);
  int* csr_src = (int*)alloc((size_t)E * 4);
  float* csr_w = (float*)alloc((size_t)E * 4);
  float* ew = (float*)alloc((size_t)E * 4);
  float* cvec = (float*)alloc(H * 4);
  unsigned short* wpk = (unsigned short*)alloc((size_t)9 * 16384 * 2);
  unsigned short* xbf = (unsigned short*)alloc((size_t)N * H * 2);
  unsigned short* buf1 = (unsigned short*)alloc((size_t)N * H * 2);  // hbf / aggbf
  float* hbuf = (float*)alloc((size_t)N * H * 4);                    // h f32 / Abf+Bbf

  unsigned short* hbf = buf1;
  unsigned short* aggbf = buf1;
  unsigned short* Abf = (unsigned short*)hbuf;
  unsigned short* Bbf = (unsigned short*)hbuf + (size_t)N * H;

  hipLaunchKernelGGL(zero_int_kernel, dim3((N + 255) / 256), dim3(256), 0, stream, cnt, N);
  hipLaunchKernelGGL(prep_cvec_kernel, dim3(1), dim3(H), 0, stream, Wf, bf, cvec);
  hipLaunchKernelGGL(count_kernel, dim3((E + 255) / 256), dim3(256), 0, stream, ei, E, cnt);
  hipLaunchKernelGGL(scan_kernel, dim3(1), dim3(1024), 0, stream, cnt, off, pos, N);
  hipLaunchKernelGGL(edge_weight_v3_kernel, dim3(4096), dim3(256), 0, stream, af, We1, be1,
                     We2, be2, ew, E);
  hipLaunchKernelGGL(fill_kernel, dim3((E + 255) / 256), dim3(256), 0, stream, ei, ew, E, pos,
                     csr_src, csr_w);
  hipLaunchKernelGGL(cvt_bf16_kernel, dim3(((long)N * H / 8 + 255) / 256), dim3(256), 0, stream,
                     h_old, hbf, (long)N * H);
  hipLaunchKernelGGL(pack_w_kernel, dim3(72), dim3(256), 0, stream, Wf, Wrel, Wroot, Wd1, wpk);

  int gblocks = (N + 255) / 256;
  // x = relu(h_old @ Wf2 + cvec) -> bf16
  hipLaunchKernelGGL((mfma_gemm_kernel<false, 1>), dim3(gblocks), dim3(256), 0, stream, hbf,
                     wpk, (const unsigned short*)nullptr, (const unsigned short*)nullptr, cvec,
                     xbf, N);

  for (int l = 0; l < 3; ++l) {
    hipLaunchKernelGGL(gather_agg_bf_kernel, dim3((N + 3) / 4), dim3(256), 0, stream, xbf, off,
                       csr_src, csr_w, aggbf, N);
    hipLaunchKernelGGL((mfma_gemm_kernel<true, 0>), dim3(gblocks), dim3(256), 0, stream, aggbf,
                       wpk + (size_t)(1 + l) * 16384, xbf, wpk + (size_t)(4 + l) * 16384,
                       brel + l * H, hbuf, N);
    hipLaunchKernelGGL(ln_relu_res_bf_kernel, dim3((N + 3) / 4), dim3(256), 0, stream, hbuf,
                       xbf, gamma + l * H, beta + l * H, N);
  }

  // decoder per-node projections: A = x@Wd1a + bd1 ; B = x@Wd1b  (bf16 outputs)
  hipLaunchKernelGGL((mfma_gemm_kernel<false, 2>), dim3(gblocks), dim3(256), 0, stream, xbf,
                     wpk + (size_t)7 * 16384, (const unsigned short*)nullptr,
                     (const unsigned short*)nullptr, bd1, Abf, N);
  hipLaunchKernelGGL((mfma_gemm_kernel<false, 2>), dim3(gblocks), dim3(256), 0, stream, xbf,
                     wpk + (size_t)8 * 16384, (const unsigned short*)nullptr,
                     (const unsigned short*)nullptr, (const float*)nullptr, Bbf, N);
  hipLaunchKernelGGL(edge_out_v3_kernel, dim3(4096), dim3(256), 0, stream, ei, af, Abf, Bbf,
                     Wd1 + 2 * H * H, Wd2, bd2, out, E);
}

// Round 7
// 466.081 us; speedup vs baseline: 1.1180x; 1.1000x over previous
//
#include <hip/hip_runtime.h>
#include <hip/hip_bf16.h>

#define H 128
#define LN_EPS 1e-5f

typedef __attribute__((ext_vector_type(8))) short bf16x8;
typedef __attribute__((ext_vector_type(4))) float f32x4;

static __device__ __forceinline__ unsigned short f2bf(float f) {
  unsigned u = __float_as_uint(f);
  unsigned r = (u + 0x7fff + ((u >> 16) & 1)) >> 16;
  return (unsigned short)r;
}
static __device__ __forceinline__ float bf2f(unsigned short s) {
  return __uint_as_float(((unsigned)s) << 16);
}

// ---------------- utility kernels ----------------

__global__ void zero_int_kernel(int* __restrict__ p, int n) {
  int i = blockIdx.x * blockDim.x + threadIdx.x;
  if (i < n) p[i] = 0;
}

// cvec[j] = bf[j] + sum_{r<128} Wf[r][j]   (the ones @ Wf[:128] term)
__global__ __launch_bounds__(1024) void prep_cvec_kernel(const float* __restrict__ Wf,
                                                         const float* __restrict__ bf,
                                                         float* __restrict__ cvec) {
  __shared__ float part[8][128];
  int tid = threadIdx.x;
  int col = tid & 127, seg = tid >> 7;
  float s = 0.f;
  for (int r = seg * 16; r < seg * 16 + 16; ++r) s += Wf[r * H + col];
  part[seg][col] = s;
  __syncthreads();
  if (tid < 128) {
    float t = bf[tid];
#pragma unroll
    for (int g = 0; g < 8; ++g) t += part[g][tid];
    cvec[tid] = t;
  }
}

__global__ void count_kernel(const int* __restrict__ ei, int E, int* __restrict__ cnt) {
  int e = blockIdx.x * blockDim.x + threadIdx.x;
  if (e < E) atomicAdd(&cnt[ei[E + e]], 1);  // dst = ei[1][e]
}

__global__ __launch_bounds__(1024) void scan_kernel(const int* __restrict__ cnt,
                                                    int* __restrict__ off,
                                                    int* __restrict__ pos, int N) {
  __shared__ int wtot[16];
  __shared__ int wbase[16];
  __shared__ int s_btot;
  __shared__ int s_carry;
  int tid = threadIdx.x, lane = tid & 63, wid = tid >> 6;
  if (tid == 0) s_carry = 0;
  __syncthreads();
  for (int base = 0; base < N; base += 4096) {
    int i0 = base + tid * 4;
    int v[4];
#pragma unroll
    for (int j = 0; j < 4; ++j) v[j] = (i0 + j < N) ? cnt[i0 + j] : 0;
    int s = v[0] + v[1] + v[2] + v[3];
    int incl = s;
#pragma unroll
    for (int o = 1; o < 64; o <<= 1) {
      int t = __shfl_up(incl, o, 64);
      if (lane >= o) incl += t;
    }
    if (lane == 63) wtot[wid] = incl;
    __syncthreads();
    if (tid == 0) {
      int run = 0;
      for (int w = 0; w < 16; ++w) { wbase[w] = run; run += wtot[w]; }
      s_btot = run;
    }
    __syncthreads();
    int e0 = s_carry + wbase[wid] + (incl - s);
#pragma unroll
    for (int j = 0; j < 4; ++j) {
      if (i0 + j < N) { off[i0 + j] = e0; pos[i0 + j] = e0; }
      e0 += v[j];
    }
    __syncthreads();
    if (tid == 0) s_carry += s_btot;
    __syncthreads();
  }
  if (tid == 0) off[N] = s_carry;
}

// packed CSR entry: (src, weight bits)
__global__ void fill_kernel(const int* __restrict__ ei, const float* __restrict__ ew, int E,
                            int* __restrict__ pos, uint2* __restrict__ csr) {
  int e = blockIdx.x * blockDim.x + threadIdx.x;
  if (e < E) {
    int d = ei[E + e];
    int p = atomicAdd(&pos[d], 1);
    csr[p] = make_uint2((unsigned)ei[e], __float_as_uint(ew[e]));
  }
}

// pack 9 [128x128] weight matrices into MFMA B-fragment layout:
// wpk[m*16384 + ((kk*8+nf)*64 + l)*8 + j] = bf16(W[kk*32 + (l>>4)*8 + j][nf*16 + (l&15)])
__global__ __launch_bounds__(256) void pack_w_kernel(const float* __restrict__ Wf,
                                                     const float* __restrict__ Wrel,
                                                     const float* __restrict__ Wroot,
                                                     const float* __restrict__ Wd1,
                                                     unsigned short* __restrict__ wpk) {
  int id = blockIdx.x * blockDim.x + threadIdx.x;  // 0 .. 9*2048-1
  if (id >= 9 * 2048) return;
  int l = id & 63, nf = (id >> 6) & 7, kk = (id >> 9) & 3, m = id >> 11;
  const float* src;
  if (m == 0) src = Wf + H * H;                       // Wf2 (h_old part)
  else if (m <= 3) src = Wrel + (size_t)(m - 1) * H * H;
  else if (m <= 6) src = Wroot + (size_t)(m - 4) * H * H;
  else src = Wd1 + (size_t)(m - 7) * H * H;           // Wd1a, Wd1b
  int col = nf * 16 + (l & 15);
  int kbase = kk * 32 + (l >> 4) * 8;
  unsigned short t[8];
#pragma unroll
  for (int j = 0; j < 8; ++j) t[j] = f2bf(src[(size_t)(kbase + j) * H + col]);
  *(uint4*)&wpk[(size_t)id * 8] = *(uint4*)t;
}

// ---------------- edge weight MLP v3: 16 lanes/edge, weights in registers ----------------
__global__ __launch_bounds__(256) void edge_weight_v3_kernel(
    const float* __restrict__ af, const float* __restrict__ We1, const float* __restrict__ be1,
    const float* __restrict__ We2, const float* __restrict__ be2, float* __restrict__ ew, int E) {
  int lane = threadIdx.x & 63;
  int sub = lane & 15;
  int grp = lane >> 4;
  float w1[8][8], b1[8], w2[8];
#pragma unroll
  for (int i = 0; i < 8; ++i)
#pragma unroll
    for (int c = 0; c < 8; ++c) w1[i][c] = We1[i * H + sub * 8 + c];
#pragma unroll
  for (int c = 0; c < 8; ++c) { b1[c] = be1[sub * 8 + c]; w2[c] = We2[sub * 8 + c]; }
  float b2 = be2[0];
  int gw = (blockIdx.x * blockDim.x + threadIdx.x) >> 6;
  int nw = (gridDim.x * blockDim.x) >> 6;
  int n4 = (E + 3) >> 2;
  for (int e4 = gw; e4 < n4; e4 += nw) {
    int e = e4 * 4 + grp;
    bool valid = e < E;
    int ee = valid ? e : E - 1;
    float4 a0 = *(const float4*)&af[(size_t)ee * 8];
    float4 a1 = *(const float4*)&af[(size_t)ee * 8 + 4];
    float afv[8] = {a0.x, a0.y, a0.z, a0.w, a1.x, a1.y, a1.z, a1.w};
    float t[8];
#pragma unroll
    for (int c = 0; c < 8; ++c) t[c] = b1[c];
#pragma unroll
    for (int i = 0; i < 8; ++i)
#pragma unroll
      for (int c = 0; c < 8; ++c) t[c] += afv[i] * w1[i][c];
    float p = 0.f;
#pragma unroll
    for (int c = 0; c < 8; ++c) p += fmaxf(t[c], 0.f) * w2[c];
    p += __shfl_xor(p, 1, 64);
    p += __shfl_xor(p, 2, 64);
    p += __shfl_xor(p, 4, 64);
    p += __shfl_xor(p, 8, 64);
    if (valid && sub == 0) {
      float s = p + b2;
      ew[e] = 1.f / (1.f + expf(-s));
    }
  }
}

// ---------------- init GEMM: xbf = relu(h_old(f32) @ Wf2 + cvec), MI=2 ----------------
__global__ __launch_bounds__(256) void gemm_init_kernel(
    const float* __restrict__ Xf, const unsigned short* __restrict__ Wp,
    const float* __restrict__ bias, unsigned short* __restrict__ Y, int M) {
  int l = threadIdx.x & 63, w = threadIdx.x >> 6;
  int lr = l & 15, lg = l >> 4;
  int m0 = blockIdx.x * 128 + w * 32;
  f32x4 acc[2][8] = {};
  for (int kk = 0; kk < 4; ++kk) {
    bf16x8 a[2];
#pragma unroll
    for (int mi = 0; mi < 2; ++mi) {
      int row = m0 + mi * 16 + lr;
      if (row >= M) row = M - 1;
      const float* xp = &Xf[(size_t)row * H + kk * 32 + lg * 8];
      float4 u0 = *(const float4*)xp;
      float4 u1 = *(const float4*)(xp + 4);
      unsigned short t[8] = {f2bf(u0.x), f2bf(u0.y), f2bf(u0.z), f2bf(u0.w),
                             f2bf(u1.x), f2bf(u1.y), f2bf(u1.z), f2bf(u1.w)};
      a[mi] = *(const bf16x8*)t;
    }
#pragma unroll
    for (int nf = 0; nf < 8; ++nf) {
      bf16x8 b = *(const bf16x8*)&Wp[(size_t)(kk * 8 + nf) * 512 + l * 8];
#pragma unroll
      for (int mi = 0; mi < 2; ++mi)
        acc[mi][nf] = __builtin_amdgcn_mfma_f32_16x16x32_bf16(a[mi], b, acc[mi][nf], 0, 0, 0);
    }
  }
  float bv[8];
#pragma unroll
  for (int nf = 0; nf < 8; ++nf) bv[nf] = bias[nf * 16 + lr];
#pragma unroll
  for (int mi = 0; mi < 2; ++mi)
#pragma unroll
    for (int r = 0; r < 4; ++r) {
      int row = m0 + mi * 16 + lg * 4 + r;
      if (row < M) {
#pragma unroll
        for (int nf = 0; nf < 8; ++nf)
          Y[(size_t)row * H + nf * 16 + lr] = f2bf(fmaxf(acc[mi][nf][r] + bv[nf], 0.f));
      }
    }
}

// ---------------- layer GEMM + LN + relu + residual (in-place x), MI=2 ----------------
// h = agg@Wrel + brel + x@Wroot ; x = bf16(relu(LN(h)*g+b) + x)
__global__ __launch_bounds__(256) void gemm_layer_ln_kernel(
    const unsigned short* __restrict__ Agg, const unsigned short* __restrict__ WpRel,
    unsigned short* __restrict__ Xio, const unsigned short* __restrict__ WpRoot,
    const float* __restrict__ brel, const float* __restrict__ gamma,
    const float* __restrict__ beta, int M) {
  int l = threadIdx.x & 63, w = threadIdx.x >> 6;
  int lr = l & 15, lg = l >> 4;
  int m0 = blockIdx.x * 128 + w * 32;
  f32x4 acc[2][8] = {};
  for (int kk = 0; kk < 8; ++kk) {
    const unsigned short* X = (kk >= 4) ? Xio : Agg;
    const unsigned short* Wp = (kk >= 4) ? WpRoot : WpRel;
    int k4 = kk & 3;
    bf16x8 a[2] = {};  // zero-fill for row>=M: avoids reading rows another block may write
#pragma unroll
    for (int mi = 0; mi < 2; ++mi) {
      int row = m0 + mi * 16 + lr;
      if (row < M) a[mi] = *(const bf16x8*)&X[(size_t)row * H + k4 * 32 + lg * 8];
    }
#pragma unroll
    for (int nf = 0; nf < 8; ++nf) {
      bf16x8 b = *(const bf16x8*)&Wp[(size_t)(k4 * 8 + nf) * 512 + l * 8];
#pragma unroll
      for (int mi = 0; mi < 2; ++mi)
        acc[mi][nf] = __builtin_amdgcn_mfma_f32_16x16x32_bf16(a[mi], b, acc[mi][nf], 0, 0, 0);
    }
  }
  float bv[8], gv[8], bev[8];
#pragma unroll
  for (int nf = 0; nf < 8; ++nf) {
    int col = nf * 16 + lr;
    bv[nf] = brel[col]; gv[nf] = gamma[col]; bev[nf] = beta[col];
  }
#pragma unroll
  for (int mi = 0; mi < 2; ++mi) {
#pragma unroll
    for (int r = 0; r < 4; ++r) {
      int row = m0 + mi * 16 + lg * 4 + r;
      float hv[8], s1 = 0.f;
#pragma unroll
      for (int nf = 0; nf < 8; ++nf) { hv[nf] = acc[mi][nf][r] + bv[nf]; s1 += hv[nf]; }
      s1 += __shfl_xor(s1, 1, 64);
      s1 += __shfl_xor(s1, 2, 64);
      s1 += __shfl_xor(s1, 4, 64);
      s1 += __shfl_xor(s1, 8, 64);
      float mu = s1 * (1.0f / H);
      float s2 = 0.f;
#pragma unroll
      for (int nf = 0; nf < 8; ++nf) { float d = hv[nf] - mu; s2 += d * d; }
      s2 += __shfl_xor(s2, 1, 64);
      s2 += __shfl_xor(s2, 2, 64);
      s2 += __shfl_xor(s2, 4, 64);
      s2 += __shfl_xor(s2, 8, 64);
      float rstd = rsqrtf(s2 * (1.0f / H) + LN_EPS);
      if (row < M) {
#pragma unroll
        for (int nf = 0; nf < 8; ++nf) {
          int col = nf * 16 + lr;
          float v = fmaxf((hv[nf] - mu) * rstd * gv[nf] + bev[nf], 0.f);
          v += bf2f(Xio[(size_t)row * H + col]);
          Xio[(size_t)row * H + col] = f2bf(v);
        }
      }
    }
  }
}

// ---------------- decoder GEMMs fused: A = x@Wd1a + bd1 ; B = x@Wd1b, MI=2 ----------------
__global__ __launch_bounds__(256) void gemm_dec_kernel(
    const unsigned short* __restrict__ X, const unsigned short* __restrict__ WpA,
    const unsigned short* __restrict__ WpB, const float* __restrict__ bd1,
    unsigned short* __restrict__ Aout, unsigned short* __restrict__ Bout, int M) {
  int l = threadIdx.x & 63, w = threadIdx.x >> 6;
  int lr = l & 15, lg = l >> 4;
  int m0 = blockIdx.x * 128 + w * 32;
  f32x4 accA[2][8] = {};
  f32x4 accB[2][8] = {};
  for (int kk = 0; kk < 4; ++kk) {
    bf16x8 a[2];
#pragma unroll
    for (int mi = 0; mi < 2; ++mi) {
      int row = m0 + mi * 16 + lr;
      if (row >= M) row = M - 1;
      a[mi] = *(const bf16x8*)&X[(size_t)row * H + kk * 32 + lg * 8];
    }
#pragma unroll
    for (int nf = 0; nf < 8; ++nf) {
      bf16x8 bA = *(const bf16x8*)&WpA[(size_t)(kk * 8 + nf) * 512 + l * 8];
      bf16x8 bB = *(const bf16x8*)&WpB[(size_t)(kk * 8 + nf) * 512 + l * 8];
#pragma unroll
      for (int mi = 0; mi < 2; ++mi) {
        accA[mi][nf] = __builtin_amdgcn_mfma_f32_16x16x32_bf16(a[mi], bA, accA[mi][nf], 0, 0, 0);
        accB[mi][nf] = __builtin_amdgcn_mfma_f32_16x16x32_bf16(a[mi], bB, accB[mi][nf], 0, 0, 0);
      }
    }
  }
  float bdv[8];
#pragma unroll
  for (int nf = 0; nf < 8; ++nf) bdv[nf] = bd1[nf * 16 + lr];
#pragma unroll
  for (int mi = 0; mi < 2; ++mi)
#pragma unroll
    for (int r = 0; r < 4; ++r) {
      int row = m0 + mi * 16 + lg * 4 + r;
      if (row < M) {
#pragma unroll
        for (int nf = 0; nf < 8; ++nf) {
          int col = nf * 16 + lr;
          Aout[(size_t)row * H + col] = f2bf(accA[mi][nf][r] + bdv[nf]);
          Bout[(size_t)row * H + col] = f2bf(accB[mi][nf][r]);
        }
      }
    }
}

// ---------------- gather: agg[n] = sum_in-edges w * x[src] (wave/node, masked 8-chunks) ----------------
__global__ __launch_bounds__(256) void gather_agg_v2_kernel(
    const unsigned short* __restrict__ xbf, const int* __restrict__ off,
    const uint2* __restrict__ csr, unsigned short* __restrict__ aggbf, int N) {
  int gw = (blockIdx.x * blockDim.x + threadIdx.x) >> 6;
  int lane = threadIdx.x & 63;
  int nw = (gridDim.x * blockDim.x) >> 6;
  for (int n = gw; n < N; n += nw) {
    int s0 = off[n], s1 = off[n + 1];
    float ax = 0.f, ay = 0.f;
    for (int base = s0; base < s1; base += 8) {
      unsigned srcv[8];
      float wv[8];
#pragma unroll
      for (int j = 0; j < 8; ++j) {
        int id = base + j;
        int cid = id < s1 ? id : s1 - 1;  // clamped (s1 > s0 guaranteed in loop)
        uint2 c = csr[cid];
        srcv[j] = c.x;
        wv[j] = (id < s1) ? __uint_as_float(c.y) : 0.f;
      }
      unsigned vv[8];
#pragma unroll
      for (int j = 0; j < 8; ++j)
        vv[j] = *(const unsigned*)&xbf[(size_t)srcv[j] * H + lane * 2];
#pragma unroll
      for (int j = 0; j < 8; ++j) {
        ax += wv[j] * bf2f((unsigned short)(vv[j] & 0xffffu));
        ay += wv[j] * bf2f((unsigned short)(vv[j] >> 16));
      }
    }
    unsigned o = (unsigned)f2bf(ax) | ((unsigned)f2bf(ay) << 16);
    *(unsigned*)&aggbf[(size_t)n * H + lane * 2] = o;
  }
}

// ---------------- edge decoder v3: 16 lanes/edge, weights in registers ----------------
__global__ __launch_bounds__(256) void edge_out_v3_kernel(
    const int* __restrict__ ei, const float* __restrict__ af,
    const unsigned short* __restrict__ A, const unsigned short* __restrict__ B,
    const float* __restrict__ Wd1c, const float* __restrict__ Wd2,
    const float* __restrict__ bd2, float* __restrict__ out, int E) {
  int lane = threadIdx.x & 63;
  int sub = lane & 15;
  int grp = lane >> 4;
  float wc[8][8], w2[8];
#pragma unroll
  for (int i = 0; i < 8; ++i)
#pragma unroll
    for (int c = 0; c < 8; ++c) wc[i][c] = Wd1c[i * H + sub * 8 + c];
#pragma unroll
  for (int c = 0; c < 8; ++c) w2[c] = Wd2[sub * 8 + c];
  float b2 = bd2[0];
  int gw = (blockIdx.x * blockDim.x + threadIdx.x) >> 6;
  int nw = (gridDim.x * blockDim.x) >> 6;
  int n4 = (E + 3) >> 2;
  for (int e4 = gw; e4 < n4; e4 += nw) {
    int e = e4 * 4 + grp;
    bool valid = e < E;
    int ee = valid ? e : E - 1;
    int s = ei[ee], d = ei[E + ee];
    uint4 va = *(const uint4*)&A[(size_t)s * H + sub * 8];
    uint4 vb = *(const uint4*)&B[(size_t)d * H + sub * 8];
    float4 a0 = *(const float4*)&af[(size_t)ee * 8];
    float4 a1 = *(const float4*)&af[(size_t)ee * 8 + 4];
    float afv[8] = {a0.x, a0.y, a0.z, a0.w, a1.x, a1.y, a1.z, a1.w};
    const unsigned* pa = (const unsigned*)&va;
    const unsigned* pb = (const unsigned*)&vb;
    float t[8];
#pragma unroll
    for (int q = 0; q < 4; ++q) {
      unsigned av = pa[q], bv = pb[q];
      t[q * 2 + 0] = bf2f((unsigned short)(av & 0xffffu)) + bf2f((unsigned short)(bv & 0xffffu));
      t[q * 2 + 1] = bf2f((unsigned short)(av >> 16)) + bf2f((unsigned short)(bv >> 16));
    }
#pragma unroll
    for (int i = 0; i < 8; ++i)
#pragma unroll
      for (int c = 0; c < 8; ++c) t[c] += afv[i] * wc[i][c];
    float p = 0.f;
#pragma unroll
    for (int c = 0; c < 8; ++c) p += fmaxf(t[c], 0.f) * w2[c];
    p += __shfl_xor(p, 1, 64);
    p += __shfl_xor(p, 2, 64);
    p += __shfl_xor(p, 4, 64);
    p += __shfl_xor(p, 8, 64);
    if (valid && sub == 0) out[e] = p + b2;
  }
}

// ---------------- launch ----------------
extern "C" void kernel_launch(void* const* d_in, const int* in_sizes, int n_in, void* d_out,
                              int out_size, void* d_ws, size_t ws_size, hipStream_t stream) {
  const int* ei = (const int*)d_in[0];
  const float* af = (const float*)d_in[1];
  const float* h_old = (const float*)d_in[2];
  const float* Wf = (const float*)d_in[4];
  const float* bf = (const float*)d_in[5];
  const float* We1 = (const float*)d_in[6];
  const float* be1 = (const float*)d_in[7];
  const float* We2 = (const float*)d_in[8];
  const float* be2 = (const float*)d_in[9];
  const float* Wrel = (const float*)d_in[10];
  const float* brel = (const float*)d_in[11];
  const float* Wroot = (const float*)d_in[12];
  const float* gamma = (const float*)d_in[13];
  const float* beta = (const float*)d_in[14];
  const float* Wd1 = (const float*)d_in[15];
  const float* bd1 = (const float*)d_in[16];
  const float* Wd2 = (const float*)d_in[17];
  const float* bd2 = (const float*)d_in[18];
  const int N = in_sizes[2] / H;
  const int E = in_sizes[1] / 8;
  float* out = (float*)d_out;

  char* p = (char*)d_ws;
  auto alloc = [&](size_t b) { char* r = p; p += (b + 255) & ~(size_t)255; return r; };
  int* cnt = (int*)alloc((size_t)N * 4);
  int* pos = (int*)alloc((size_t)N * 4);
  int* off = (int*)alloc((size_t)(N + 1) * 4);
  uint2* csr = (uint2*)alloc((size_t)E * 8);
  float* ew = (float*)alloc((size_t)E * 4);
  float* cvec = (float*)alloc(H * 4);
  unsigned short* wpk = (unsigned short*)alloc((size_t)9 * 16384 * 2);
  unsigned short* xbf = (unsigned short*)alloc((size_t)N * H * 2);
  unsigned short* aggbf = (unsigned short*)alloc((size_t)N * H * 2);
  unsigned short* buf2 = (unsigned short*)alloc((size_t)N * H * 2);

  unsigned short* Abf = aggbf;  // reuse after layer loop
  unsigned short* Bbf = buf2;

  hipLaunchKernelGGL(zero_int_kernel, dim3((N + 255) / 256), dim3(256), 0, stream, cnt, N);
  hipLaunchKernelGGL(prep_cvec_kernel, dim3(1), dim3(1024), 0, stream, Wf, bf, cvec);
  hipLaunchKernelGGL(count_kernel, dim3((E + 255) / 256), dim3(256), 0, stream, ei, E, cnt);
  hipLaunchKernelGGL(scan_kernel, dim3(1), dim3(1024), 0, stream, cnt, off, pos, N);
  hipLaunchKernelGGL(edge_weight_v3_kernel, dim3(4096), dim3(256), 0, stream, af, We1, be1,
                     We2, be2, ew, E);
  hipLaunchKernelGGL(fill_kernel, dim3((E + 255) / 256), dim3(256), 0, stream, ei, ew, E, pos,
                     csr);
  hipLaunchKernelGGL(pack_w_kernel, dim3(72), dim3(256), 0, stream, Wf, Wrel, Wroot, Wd1, wpk);

  int gblocks = (N + 127) / 128;
  // x = relu(h_old @ Wf2 + cvec) -> bf16 (f32 input converted in-register)
  hipLaunchKernelGGL(gemm_init_kernel, dim3(gblocks), dim3(256), 0, stream, h_old, wpk, cvec,
                     xbf, N);

  for (int l = 0; l < 3; ++l) {
    hipLaunchKernelGGL(gather_agg_v2_kernel, dim3((N + 3) / 4), dim3(256), 0, stream, xbf, off,
                       csr, aggbf, N);
    hipLaunchKernelGGL(gemm_layer_ln_kernel, dim3(gblocks), dim3(256), 0, stream, aggbf,
                       wpk + (size_t)(1 + l) * 16384, xbf, wpk + (size_t)(4 + l) * 16384,
                       brel + l * H, gamma + l * H, beta + l * H, N);
  }

  // decoder per-node projections in one pass: A = x@Wd1a + bd1 ; B = x@Wd1b
  hipLaunchKernelGGL(gemm_dec_kernel, dim3(gblocks), dim3(256), 0, stream, xbf,
                     wpk + (size_t)7 * 16384, wpk + (size_t)8 * 16384, bd1, Abf, Bbf, N);
  hipLaunchKernelGGL(edge_out_v3_kernel, dim3(4096), dim3(256), 0, stream, ei, af, Abf, Bbf,
                     Wd1 + 2 * H * H, Wd2, bd2, out, E);
}